// Round 1
// baseline (835.108 us; speedup 1.0000x reference)
//
#include <hip/hip_runtime.h>
#include <stdint.h>

#define NROWS 32768   // 32*32*32
#define NCODE 4096
#define CDIM  256
#define KDIM  1024

static __device__ __forceinline__ unsigned int f2ord(float f) {
    unsigned int b = __float_as_uint(f);
    return (b & 0x80000000u) ? ~b : (b | 0x80000000u);
}

// ---------------- kernel 1: e = codebook @ proj_w^T + proj_b ----------------
// (4096 x 256), K=1024.  BM=64 codes, BN=64 dims, BK=32, 256 thr, 4x4 micro.
extern "C" __global__ __launch_bounds__(256)
void k_proj(const float* __restrict__ cb, const float* __restrict__ pw,
            const float* __restrict__ pb, float* __restrict__ e)
{
    __shared__ __align__(16) float As[32][68];
    __shared__ __align__(16) float Bs[32][68];
    const int tid = threadIdx.x;
    const int tx = tid & 15, ty = tid >> 4;
    const int bm = blockIdx.x;   // 64 code tiles
    const int bn = blockIdx.y;   // 4 dim tiles
    float acc[4][4] = {};
    for (int k0 = 0; k0 < KDIM; k0 += 32) {
#pragma unroll
        for (int i = 0; i < 2; ++i) {
            int idx = tid + i * 256;          // [0,512) float4 slots
            int row = idx >> 3;               // 8 slots per row
            int kg  = (idx & 7) << 2;
            float4 va = *(const float4*)(cb + (size_t)(bm * 64 + row) * KDIM + k0 + kg);
            As[kg + 0][row] = va.x; As[kg + 1][row] = va.y;
            As[kg + 2][row] = va.z; As[kg + 3][row] = va.w;
            float4 vb = *(const float4*)(pw + (size_t)(bn * 64 + row) * KDIM + k0 + kg);
            Bs[kg + 0][row] = vb.x; Bs[kg + 1][row] = vb.y;
            Bs[kg + 2][row] = vb.z; Bs[kg + 3][row] = vb.w;
        }
        __syncthreads();
#pragma unroll
        for (int k = 0; k < 32; ++k) {
            float4 a = *(const float4*)&As[k][ty * 4];
            float4 b = *(const float4*)&Bs[k][tx * 4];
            float av[4] = {a.x, a.y, a.z, a.w};
            float bv[4] = {b.x, b.y, b.z, b.w};
#pragma unroll
            for (int i = 0; i < 4; ++i)
#pragma unroll
                for (int j = 0; j < 4; ++j)
                    acc[i][j] = fmaf(av[i], bv[j], acc[i][j]);
        }
        __syncthreads();
    }
    const int col0 = bn * 64 + tx * 4;
    float4 bias = *(const float4*)(pb + col0);
    float bb[4] = {bias.x, bias.y, bias.z, bias.w};
#pragma unroll
    for (int i = 0; i < 4; ++i) {
        int row = bm * 64 + ty * 4 + i;
        float4 o;
        o.x = acc[i][0] + bb[0]; o.y = acc[i][1] + bb[1];
        o.z = acc[i][2] + bb[2]; o.w = acc[i][3] + bb[3];
        *(float4*)(e + (size_t)row * CDIM + col0) = o;
    }
}

// ---------------- kernel 1b: ||e_j||^2 ----------------
extern "C" __global__ __launch_bounds__(256)
void k_enorm(const float* __restrict__ e, float* __restrict__ en)
{
    int code = blockIdx.x * 4 + (threadIdx.x >> 6);
    int lane = threadIdx.x & 63;
    float4 v = *(const float4*)(e + (size_t)code * CDIM + lane * 4);
    float s = v.x * v.x + v.y * v.y + v.z * v.z + v.w * v.w;
#pragma unroll
    for (int off = 1; off < 64; off <<= 1) s += __shfl_xor(s, off);
    if (lane == 0) en[code] = s;
}

// ---------------- kernel 1c: init argmin keys ----------------
extern "C" __global__ __launch_bounds__(256)
void k_init(unsigned long long* __restrict__ keys)
{
    int i = blockIdx.x * 256 + threadIdx.x;
    if (i < NROWS) keys[i] = 0xFFFFFFFFFFFFFFFFULL;
}

// ---------------- kernel 2: fused score-GEMM + argmin ----------------
// scores s = z @ e^T  (32768 x 4096, K=256); minimize en[c] - 2 s.
// BM=128 rows, BN=128 codes, BK=16, 256 thr, 8x8 split micro-tile.
extern "C" __global__ __launch_bounds__(256)
void k_dist(const float* __restrict__ z, const float* __restrict__ e,
            const float* __restrict__ en, unsigned long long* __restrict__ keys)
{
    __shared__ __align__(16) float As[16][132];
    __shared__ __align__(16) float Bs[16][132];
    const int tid = threadIdx.x;
    const int tx = tid & 15, ty = tid >> 4;
    const int bR = blockIdx.x;   // 256 row tiles
    const int bC = blockIdx.y;   // 32 col tiles
    float acc[8][8] = {};
    for (int k0 = 0; k0 < CDIM; k0 += 16) {
#pragma unroll
        for (int i = 0; i < 2; ++i) {
            int idx = tid + i * 256;          // [0,512) float4 slots
            int row = idx >> 2;               // 4 slots per row
            int kg  = (idx & 3) << 2;
            float4 va = *(const float4*)(z + (size_t)(bR * 128 + row) * CDIM + k0 + kg);
            As[kg + 0][row] = va.x; As[kg + 1][row] = va.y;
            As[kg + 2][row] = va.z; As[kg + 3][row] = va.w;
            float4 vb = *(const float4*)(e + (size_t)(bC * 128 + row) * CDIM + k0 + kg);
            Bs[kg + 0][row] = vb.x; Bs[kg + 1][row] = vb.y;
            Bs[kg + 2][row] = vb.z; Bs[kg + 3][row] = vb.w;
        }
        __syncthreads();
#pragma unroll
        for (int k = 0; k < 16; ++k) {
            float4 a0 = *(const float4*)&As[k][ty * 4];
            float4 a1 = *(const float4*)&As[k][64 + ty * 4];
            float4 b0 = *(const float4*)&Bs[k][tx * 4];
            float4 b1 = *(const float4*)&Bs[k][64 + tx * 4];
            float av[8] = {a0.x, a0.y, a0.z, a0.w, a1.x, a1.y, a1.z, a1.w};
            float bv[8] = {b0.x, b0.y, b0.z, b0.w, b1.x, b1.y, b1.z, b1.w};
#pragma unroll
            for (int i = 0; i < 8; ++i)
#pragma unroll
                for (int j = 0; j < 8; ++j)
                    acc[i][j] = fmaf(av[i], bv[j], acc[i][j]);
        }
        __syncthreads();
    }
    // epilogue: d2' = en[col] - 2*s ; per-row argmin (key = ord(d2')<<32 | col)
    float env[8];
    {
        float4 e0 = *(const float4*)(en + bC * 128 + tx * 4);
        float4 e1 = *(const float4*)(en + bC * 128 + 64 + tx * 4);
        env[0] = e0.x; env[1] = e0.y; env[2] = e0.z; env[3] = e0.w;
        env[4] = e1.x; env[5] = e1.y; env[6] = e1.z; env[7] = e1.w;
    }
    const int colbase = bC * 128;
#pragma unroll
    for (int i = 0; i < 8; ++i) {
        unsigned long long best = 0xFFFFFFFFFFFFFFFFULL;
#pragma unroll
        for (int j = 0; j < 8; ++j) {
            int col = colbase + ((j < 4) ? (tx * 4 + j) : (64 + tx * 4 + (j - 4)));
            float d2 = env[j] - 2.0f * acc[i][j];
            unsigned long long key =
                ((unsigned long long)f2ord(d2) << 32) | (unsigned int)col;
            if (key < best) best = key;
        }
#pragma unroll
        for (int off = 8; off >= 1; off >>= 1) {
            unsigned long long o = __shfl_xor(best, off);
            if (o < best) best = o;
        }
        if (tx == 0) {
            int row = bR * 128 + ((i < 4) ? (ty * 4 + i) : (64 + ty * 4 + (i - 4)));
            atomicMin(&keys[row], best);
        }
    }
}

// ---------------- kernel 3: zidx + quant gather ----------------
extern "C" __global__ __launch_bounds__(256)
void k_out(const unsigned long long* __restrict__ keys, const float* __restrict__ e,
           float* __restrict__ out)
{
    int row  = blockIdx.x * 4 + (threadIdx.x >> 6);
    int lane = threadIdx.x & 63;
    unsigned long long key = keys[row];
    unsigned int idx = (unsigned int)(key & 0xFFFFFFFFu);
    if (lane == 0) out[row] = (float)idx;
    float4 v = *(const float4*)(e + (size_t)idx * CDIM + lane * 4);
    *(float4*)(out + NROWS + (size_t)row * CDIM + lane * 4) = v;
}

extern "C" void kernel_launch(void* const* d_in, const int* in_sizes, int n_in,
                              void* d_out, int out_size, void* d_ws, size_t ws_size,
                              hipStream_t stream)
{
    const float* encode = (const float*)d_in[0];   // 32768 x 256
    const float* cb     = (const float*)d_in[1];   // 4096 x 1024
    const float* pw     = (const float*)d_in[2];   // 256 x 1024
    const float* pb     = (const float*)d_in[3];   // 256
    float* out = (float*)d_out;                    // [32768 zidx-as-float][32768*256 quant]
    char* ws = (char*)d_ws;
    float* e  = (float*)ws;                                  // 4 MB
    float* en = (float*)(ws + 4194304);                      // 16 KB
    unsigned long long* keys = (unsigned long long*)(ws + 4194304 + 16384); // 256 KB

    k_proj <<<dim3(64, 4),  256, 0, stream>>>(cb, pw, pb, e);
    k_enorm<<<dim3(1024),   256, 0, stream>>>(e, en);
    k_init <<<dim3(128),    256, 0, stream>>>(keys);
    k_dist <<<dim3(256, 32), 256, 0, stream>>>(encode, e, en, keys);
    k_out  <<<dim3(8192),   256, 0, stream>>>(keys, e, out);
}

// Round 5
// 477.242 us; speedup vs baseline: 1.7499x; 1.7499x over previous
//
#include <hip/hip_runtime.h>
#include <hip/hip_bf16.h>
#include <stdint.h>

#define NROWS 32768   // 32*32*32
#define NCODE 4096
#define CDIM  256
#define KDIM  1024
#define NSLOT 96
#define MARGIN 1.0f

typedef __attribute__((ext_vector_type(8))) short bf16x8;
typedef __attribute__((ext_vector_type(4))) float f32x4;

static __device__ __forceinline__ unsigned f2ord(float f) {
    unsigned b = __float_as_uint(f);
    return (b & 0x80000000u) ? ~b : (b | 0x80000000u);
}
static __device__ __forceinline__ float ord2f(unsigned u) {
    unsigned b = (u & 0x80000000u) ? (u ^ 0x80000000u) : ~u;
    return __uint_as_float(b);
}
static __device__ __forceinline__ unsigned short to_bf16(float f) {
    __hip_bfloat16 h = __float2bfloat16(f);
    return *(unsigned short*)&h;
}

// ---------------- kernel 1: e = codebook @ proj_w^T + proj_b  (fp32 exact) --
extern "C" __global__ __launch_bounds__(256)
void k_proj(const float* __restrict__ cb, const float* __restrict__ pw,
            const float* __restrict__ pb, float* __restrict__ e,
            unsigned short* __restrict__ eb)
{
    __shared__ __align__(16) float As[32][68];
    __shared__ __align__(16) float Bs[32][68];
    const int tid = threadIdx.x;
    const int tx = tid & 15, ty = tid >> 4;
    const int bm = blockIdx.x;
    const int bn = blockIdx.y;
    float acc[4][4] = {};
    for (int k0 = 0; k0 < KDIM; k0 += 32) {
#pragma unroll
        for (int i = 0; i < 2; ++i) {
            int idx = tid + i * 256;
            int row = idx >> 3;
            int kg  = (idx & 7) << 2;
            float4 va = *(const float4*)(cb + (size_t)(bm * 64 + row) * KDIM + k0 + kg);
            As[kg + 0][row] = va.x; As[kg + 1][row] = va.y;
            As[kg + 2][row] = va.z; As[kg + 3][row] = va.w;
            float4 vb = *(const float4*)(pw + (size_t)(bn * 64 + row) * KDIM + k0 + kg);
            Bs[kg + 0][row] = vb.x; Bs[kg + 1][row] = vb.y;
            Bs[kg + 2][row] = vb.z; Bs[kg + 3][row] = vb.w;
        }
        __syncthreads();
#pragma unroll
        for (int k = 0; k < 32; ++k) {
            float4 a = *(const float4*)&As[k][ty * 4];
            float4 b = *(const float4*)&Bs[k][tx * 4];
            float av[4] = {a.x, a.y, a.z, a.w};
            float bv[4] = {b.x, b.y, b.z, b.w};
#pragma unroll
            for (int i = 0; i < 4; ++i)
#pragma unroll
                for (int j = 0; j < 4; ++j)
                    acc[i][j] = fmaf(av[i], bv[j], acc[i][j]);
        }
        __syncthreads();
    }
    const int col0 = bn * 64 + tx * 4;
    float4 bias = *(const float4*)(pb + col0);
    float bb[4] = {bias.x, bias.y, bias.z, bias.w};
#pragma unroll
    for (int i = 0; i < 4; ++i) {
        int row = bm * 64 + ty * 4 + i;
        float o[4];
#pragma unroll
        for (int j = 0; j < 4; ++j) o[j] = acc[i][j] + bb[j];
        *(float4*)(e + (size_t)row * CDIM + col0) = make_float4(o[0], o[1], o[2], o[3]);
        ushort4 ob;
        ob.x = to_bf16(o[0]); ob.y = to_bf16(o[1]);
        ob.z = to_bf16(o[2]); ob.w = to_bf16(o[3]);
        *(ushort4*)(eb + (size_t)row * CDIM + col0) = ob;
    }
}

// ---------------- kernel 1b: ||e_j||^2 ----------------
extern "C" __global__ __launch_bounds__(256)
void k_enorm(const float* __restrict__ e, float* __restrict__ en)
{
    int code = blockIdx.x * 4 + (threadIdx.x >> 6);
    int lane = threadIdx.x & 63;
    float4 v = *(const float4*)(e + (size_t)code * CDIM + lane * 4);
    float s = v.x * v.x + v.y * v.y + v.z * v.z + v.w * v.w;
#pragma unroll
    for (int off = 1; off < 64; off <<= 1) s += __shfl_xor(s, off);
    if (lane == 0) en[code] = s;
}

// ---------------- kernel 1c: zero candidate counters ----------------
extern "C" __global__ __launch_bounds__(256)
void k_init(unsigned* __restrict__ cnt)
{
    int i = blockIdx.x * 256 + threadIdx.x;
    if (i < NROWS) cnt[i] = 0u;
}

// ---------------- kernel 1d: z -> bf16 (FIXED: full 32B store) --------------
extern "C" __global__ __launch_bounds__(256)
void k_cvtz(const float* __restrict__ z, unsigned short* __restrict__ zb)
{
    size_t i = (size_t)blockIdx.x * 256 + threadIdx.x;   // 16 floats / thread
    const float4* src = (const float4*)(z + i * 16);
    unsigned short o[16];
#pragma unroll
    for (int q = 0; q < 4; ++q) {
        float4 v = src[q];
        o[q * 4 + 0] = to_bf16(v.x); o[q * 4 + 1] = to_bf16(v.y);
        o[q * 4 + 2] = to_bf16(v.z); o[q * 4 + 3] = to_bf16(v.w);
    }
    *(uint4*)(zb + i * 16)     = *(const uint4*)&o[0];   // 16 B
    *(uint4*)(zb + i * 16 + 8) = *(const uint4*)&o[8];   // 16 B
}

// ---------------- kernel 2: bf16 MFMA score + block argmin + candidates -----
// C(32768x4096) = z*e^T, K=256 staged in 4 quarters of 64.  Tile 128x128.
// LDS 33,280 B; XOR swizzle ((row&7)<<4) applied on BOTH ds_write and ds_read.
// Emission uses !(x > thr) so NaN scores emit -> overflow -> rerank fallback.
extern "C" __global__ __launch_bounds__(256)
void k_dist(const unsigned short* __restrict__ zb, const unsigned short* __restrict__ eb,
            const float* __restrict__ en, unsigned* __restrict__ cnt,
            unsigned* __restrict__ cand)
{
    __shared__ __align__(16) char lds[32768];     // As 16KB | Bs 16KB
    __shared__ unsigned rowmin[128];
    const int tid  = threadIdx.x;
    const int wave = tid >> 6, lane = tid & 63;
    const int bC = blockIdx.x, bR = blockIdx.y;
    const int wr = wave >> 1, wc = wave & 1;      // 2x2 waves, 64x64 out each
    const int fr = lane & 15;                     // A row / B col within frag
    const int kg = (lane >> 4) << 3;              // k sub-offset: 0,8,16,24
    if (tid < 128) rowmin[tid] = 0xFFFFFFFFu;

    char* As = lds;
    char* Bs = lds + 16384;
    const char* gz = (const char*)zb + (size_t)bR * 128 * 512;  // row = 512B
    const char* ge = (const char*)eb + (size_t)bC * 128 * 512;

    f32x4 acc[4][4] = {};

    for (int q = 0; q < 4; ++q) {                 // K quarter: k in [q*64, +64)
#pragma unroll
        for (int i = 0; i < 4; ++i) {
            int chunk = tid + i * 256;            // [0,1024) 16B chunks
            int r = chunk >> 3;                   // 8 chunks per 128B LDS row
            int w = (chunk & 7) << 4;
            int d = r * 128 + (w ^ ((r & 7) << 4));
            uint4 va = *(const uint4*)(gz + (size_t)r * 512 + q * 128 + w);
            uint4 vb = *(const uint4*)(ge + (size_t)r * 512 + q * 128 + w);
            *(uint4*)(As + d) = va;
            *(uint4*)(Bs + d) = vb;
        }
        __syncthreads();
#pragma unroll
        for (int ks = 0; ks < 2; ++ks) {
            const int kb = (ks * 32 + kg) * 2;    // byte offset in 128B row
            bf16x8 a[4], b[4];
#pragma unroll
            for (int mi = 0; mi < 4; ++mi) {
                int row = wr * 64 + mi * 16 + fr;
                a[mi] = *(const bf16x8*)(As + row * 128 + (kb ^ ((row & 7) << 4)));
            }
#pragma unroll
            for (int ni = 0; ni < 4; ++ni) {
                int row = wc * 64 + ni * 16 + fr;
                b[ni] = *(const bf16x8*)(Bs + row * 128 + (kb ^ ((row & 7) << 4)));
            }
#pragma unroll
            for (int mi = 0; mi < 4; ++mi)
#pragma unroll
                for (int ni = 0; ni < 4; ++ni)
                    acc[mi][ni] = __builtin_amdgcn_mfma_f32_16x16x32_bf16(
                        a[mi], b[ni], acc[mi][ni], 0, 0, 0);
        }
        __syncthreads();
    }

    // ---- epilogue: d~ = en[col] - 2*s ; block-local row minima ----
    const int colg0 = bC * 128 + wc * 64;
    float env[4];
#pragma unroll
    for (int ni = 0; ni < 4; ++ni) env[ni] = en[colg0 + ni * 16 + fr];
#pragma unroll
    for (int mi = 0; mi < 4; ++mi)
#pragma unroll
        for (int ni = 0; ni < 4; ++ni)
#pragma unroll
            for (int j = 0; j < 4; ++j)
                acc[mi][ni][j] = fmaf(-2.0f, acc[mi][ni][j], env[ni]);

#pragma unroll
    for (int mi = 0; mi < 4; ++mi) {
#pragma unroll
        for (int j = 0; j < 4; ++j) {
            unsigned best = 0xFFFFFFFFu;
#pragma unroll
            for (int ni = 0; ni < 4; ++ni) {
                unsigned o = f2ord(acc[mi][ni][j]);
                best = o < best ? o : best;
            }
#pragma unroll
            for (int off = 8; off >= 1; off >>= 1) {
                unsigned o = __shfl_xor(best, off);
                best = o < best ? o : best;
            }
            if (fr == 0) {
                int rl = wr * 64 + mi * 16 + ((lane >> 4) << 2) + j;
                atomicMin(&rowmin[rl], best);
            }
        }
    }
    __syncthreads();

    // ---- emission: every col within MARGIN of block-local row min.
    //      NaN-safe: !(x > thr) is TRUE for NaN -> mass-emit -> fallback.
#pragma unroll
    for (int mi = 0; mi < 4; ++mi) {
#pragma unroll
        for (int j = 0; j < 4; ++j) {
            int rl = wr * 64 + mi * 16 + ((lane >> 4) << 2) + j;
            float thr = ord2f(rowmin[rl]) + MARGIN;
#pragma unroll
            for (int ni = 0; ni < 4; ++ni) {
                if (!(acc[mi][ni][j] > thr)) {
                    int rg = bR * 128 + rl;
                    unsigned slot = atomicAdd(&cnt[rg], 1u);
                    if (slot < NSLOT)
                        cand[(size_t)rg * NSLOT + slot] =
                            (unsigned)(colg0 + ni * 16 + fr);
                }
            }
        }
    }
}

// ---------------- kernel 3: exact re-rank (f64 dot + fp32 ||e||^2) ----------
// Normal: scan candidate list. Fallback (cnt==0 or overflow): scan ALL codes.
extern "C" __global__ __launch_bounds__(256)
void k_rerank(const float* __restrict__ z, const float* __restrict__ e,
              const float* __restrict__ en, const unsigned* __restrict__ cnt,
              const unsigned* __restrict__ cand, unsigned* __restrict__ outidx)
{
    int row  = blockIdx.x * 4 + (threadIdx.x >> 6);
    int lane = threadIdx.x & 63;
    float4 zv = *(const float4*)(z + (size_t)row * CDIM + lane * 4);
    unsigned n = cnt[row];
    double best_d2 = 1e300;
    unsigned best_col = 0u;
    if (n >= 1u && n <= (unsigned)NSLOT) {
        for (unsigned i = 0; i < n; ++i) {
            unsigned col = cand[(size_t)row * NSLOT + i] & (NCODE - 1);
            const float4 ev = *(const float4*)(e + (size_t)col * CDIM + lane * 4);
            double dot = (double)zv.x * ev.x + (double)zv.y * ev.y
                       + (double)zv.z * ev.z + (double)zv.w * ev.w;
#pragma unroll
            for (int off = 1; off < 64; off <<= 1) dot += __shfl_xor(dot, off);
            double d2 = (double)en[col] - 2.0 * dot;
            if (d2 < best_d2 || (d2 == best_d2 && col < best_col)) {
                best_d2 = d2; best_col = col;
            }
        }
    } else {
        // exact full scan over all 4096 codes (safety net / diagnostic mode)
        for (unsigned col = 0; col < NCODE; ++col) {
            const float4 ev = *(const float4*)(e + (size_t)col * CDIM + lane * 4);
            double dot = (double)zv.x * ev.x + (double)zv.y * ev.y
                       + (double)zv.z * ev.z + (double)zv.w * ev.w;
#pragma unroll
            for (int off = 1; off < 64; off <<= 1) dot += __shfl_xor(dot, off);
            double d2 = (double)en[col] - 2.0 * dot;
            if (d2 < best_d2 || (d2 == best_d2 && col < best_col)) {
                best_d2 = d2; best_col = col;
            }
        }
    }
    if (lane == 0) outidx[row] = best_col;
}

// ---------------- kernel 4: zidx + quant gather (overwrites ALL of d_out) ---
extern "C" __global__ __launch_bounds__(256)
void k_out(const unsigned* __restrict__ outidx, const float* __restrict__ e,
           float* __restrict__ out)
{
    int row  = blockIdx.x * 4 + (threadIdx.x >> 6);
    int lane = threadIdx.x & 63;
    unsigned idx = outidx[row] & (NCODE - 1);
    if (lane == 0) out[row] = (float)idx;
    float4 v = *(const float4*)(e + (size_t)idx * CDIM + lane * 4);
    *(float4*)(out + NROWS + (size_t)row * CDIM + lane * 4) = v;
}

extern "C" void kernel_launch(void* const* d_in, const int* in_sizes, int n_in,
                              void* d_out, int out_size, void* d_ws, size_t ws_size,
                              hipStream_t stream)
{
    const float* encode = (const float*)d_in[0];   // 32768 x 256
    const float* cb     = (const float*)d_in[1];   // 4096 x 1024
    const float* pw     = (const float*)d_in[2];   // 256 x 1024
    const float* pb     = (const float*)d_in[3];   // 256
    float* out = (float*)d_out;

    // ws: only what k_rerank/k_out read while d_out is being rewritten.
    // 4.39 MiB total -- within the footprint round 1 proved safe.
    char* ws = (char*)d_ws;
    float*    e      = (float*)(ws);                                  // 4 MiB
    float*    en     = (float*)(ws + (4u << 20));                     // 16 KiB
    unsigned* cnt    = (unsigned*)(ws + (4u << 20) + (16u << 10));    // 128 KiB
    unsigned* outidx = (unsigned*)(ws + (4u << 20) + (144u << 10));   // 128 KiB

    // Big transients in d_out's quant region (32 MiB of scratch until k_out's
    // final full overwrite; nothing reads them after k_rerank).
    char* S = (char*)(out + NROWS);
    unsigned short* zb   = (unsigned short*)(S);               // 16 MiB
    unsigned short* eb   = (unsigned short*)(S + (16u << 20)); // 2 MiB
    unsigned*       cand = (unsigned*)(S + (18u << 20));       // 12 MiB (ends 30 MiB)

    k_proj  <<<dim3(64, 4),   256, 0, stream>>>(cb, pw, pb, e, eb);
    k_enorm <<<dim3(1024),    256, 0, stream>>>(e, en);
    k_init  <<<dim3(128),     256, 0, stream>>>(cnt);
    k_cvtz  <<<dim3(2048),    256, 0, stream>>>(encode, zb);
    k_dist  <<<dim3(32, 256), 256, 0, stream>>>(zb, eb, en, cnt, cand);
    k_rerank<<<dim3(8192),    256, 0, stream>>>(encode, e, en, cnt, cand, outidx);
    k_out   <<<dim3(8192),    256, 0, stream>>>(outidx, e, out);
}